// Round 1
// baseline (119.631 us; speedup 1.0000x reference)
//
#include <hip/hip_runtime.h>

#define B_ROWS 4096
#define N_ROWS 8192
#define DDIM   256
#define IT2    2.885390081777927f   /* 1/(T*ln2), T=0.5 */

#define BM 128
#define BN 128
#define BK 64
#define SPLITS 32
#define CT_PER_BLOCK (N_ROWS / BN / SPLITS)   /* 2 */
#define NPARTS (SPLITS * 2)

typedef unsigned short ushort_t;
typedef __bf16 bf16x8 __attribute__((ext_vector_type(8)));
typedef float  f32x4  __attribute__((ext_vector_type(4)));

__device__ __forceinline__ ushort_t f2bf(float x) {
    union { float f; unsigned u; } a; a.f = x;
    unsigned r = a.u + 0x7fffu + ((a.u >> 16) & 1u);   /* RNE */
    return (ushort_t)(r >> 16);
}

__device__ __forceinline__ void gload_lds16(const void* g, void* l) {
    __builtin_amdgcn_global_load_lds(
        (const __attribute__((address_space(1))) unsigned int*)g,
        (__attribute__((address_space(3))) unsigned int*)l,
        16, 0, 0);
}

/* ---------------- kernel 1: L2-normalize rows, emit bf16 X and norms ---- */
__global__ __launch_bounds__(256) void k_normalize(
        const float* __restrict__ feats, const float* __restrict__ tfeats,
        ushort_t* __restrict__ Xb, float* __restrict__ norms) {
    int w = threadIdx.x >> 6, l = threadIdx.x & 63;
    int row = blockIdx.x * 4 + w;                       /* grid 2048 */
    const float* src = (row < B_ROWS) ? feats + (size_t)row * DDIM
                                      : tfeats + (size_t)(row - B_ROWS) * DDIM;
    float4 v = ((const float4*)src)[l];
    float ss = v.x*v.x + v.y*v.y + v.z*v.z + v.w*v.w;
    #pragma unroll
    for (int m = 1; m < 64; m <<= 1) ss += __shfl_xor(ss, m);
    float nrm = fmaxf(sqrtf(ss), 1e-12f);
    float inv = 1.0f / nrm;
    ushort4 o;
    o.x = f2bf(v.x * inv); o.y = f2bf(v.y * inv);
    o.z = f2bf(v.z * inv); o.w = f2bf(v.w * inv);
    ((ushort4*)(Xb + (size_t)row * DDIM))[l] = o;
    if (l == 0) norms[row] = nrm;
}

/* ---------------- kernel 2: pos[i] = cos(f_i, t_i) in fp32 -------------- */
__global__ __launch_bounds__(256) void k_pos(
        const float* __restrict__ feats, const float* __restrict__ tfeats,
        const float* __restrict__ norms, float* __restrict__ posv) {
    int w = threadIdx.x >> 6, l = threadIdx.x & 63;
    int i = blockIdx.x * 4 + w;                         /* grid 1024 */
    float4 a = ((const float4*)(feats  + (size_t)i * DDIM))[l];
    float4 b = ((const float4*)(tfeats + (size_t)i * DDIM))[l];
    float d = a.x*b.x + a.y*b.y + a.z*b.z + a.w*b.w;
    #pragma unroll
    for (int m = 1; m < 64; m <<= 1) d += __shfl_xor(d, m);
    if (l == 0) posv[i] = d / (norms[i] * norms[i + B_ROWS]);
}

/* ---------------- kernel 3: fused sim-GEMM + exp + row-sum -------------- */
__global__ __launch_bounds__(256) void k_gemm(
        const ushort_t* __restrict__ Xb, float* __restrict__ parts) {
    __shared__ ushort_t ldsA[BM * BK];   /* 16 KB, swizzled content */
    __shared__ ushort_t ldsB[BN * BK];

    int bid = blockIdx.x;
    int rt = bid >> 5;                /* 0..63 row tile  */
    int split = bid & 31;             /* 0..31 col split */
    int rowbase = rt * BM;
    int t = threadIdx.x;
    int l = t & 63;
    int w = t >> 6;
    int wm = w >> 1, wn = w & 1;

    float sums[4][4];
    #pragma unroll
    for (int m = 0; m < 4; m++)
        #pragma unroll
        for (int j = 0; j < 4; j++) sums[m][j] = 0.0f;

    for (int ct = 0; ct < CT_PER_BLOCK; ++ct) {
        int colbase = (split * CT_PER_BLOCK + ct) * BN;
        f32x4 acc[4][4];
        #pragma unroll
        for (int m = 0; m < 4; m++)
            #pragma unroll
            for (int n = 0; n < 4; n++) acc[m][n] = (f32x4){0.f, 0.f, 0.f, 0.f};

        for (int kb = 0; kb < DDIM; kb += BK) {
            /* stage A[128][64] and B[128][64] bf16, pre-swizzled source so
               the linear global_load_lds dest matches the XOR-swizzled read */
            #pragma unroll
            for (int i = 0; i < 4; i++) {
                int o   = (i * 256 + t) * 16;          /* byte off in 16 KB  */
                int row = o >> 7;
                int cb  = o & 127;
                int scb = cb ^ ((row & 7) << 4);
                const char* ga = (const char*)Xb +
                    ((size_t)(rowbase + row) * DDIM + kb) * 2 + scb;
                gload_lds16(ga, (char*)ldsA + o);
                const char* gb = (const char*)Xb +
                    ((size_t)(colbase + row) * DDIM + kb) * 2 + scb;
                gload_lds16(gb, (char*)ldsB + o);
            }
            __syncthreads();

            #pragma unroll
            for (int ks = 0; ks < 2; ks++) {
                bf16x8 af[4], bfr[4];
                int cbw = ((l >> 4) * 16) + ks * 64;
                #pragma unroll
                for (int m = 0; m < 4; m++) {
                    int row  = wm * 64 + m * 16 + (l & 15);
                    int addr = row * 128 + (cbw ^ ((row & 7) << 4));
                    af[m] = *(const bf16x8*)((const char*)ldsA + addr);
                }
                #pragma unroll
                for (int n = 0; n < 4; n++) {
                    int row  = wn * 64 + n * 16 + (l & 15);
                    int addr = row * 128 + (cbw ^ ((row & 7) << 4));
                    bfr[n] = *(const bf16x8*)((const char*)ldsB + addr);
                }
                #pragma unroll
                for (int m = 0; m < 4; m++)
                    #pragma unroll
                    for (int n = 0; n < 4; n++)
                        acc[m][n] = __builtin_amdgcn_mfma_f32_16x16x32_bf16(
                            af[m], bfr[n], acc[m][n], 0, 0, 0);
            }
            __syncthreads();
        }

        /* epilogue: exp2(sim*IT2), diag -> 1.0, accumulate per-lane row sums */
        #pragma unroll
        for (int m = 0; m < 4; m++) {
            #pragma unroll
            for (int j = 0; j < 4; j++) {
                int grow = rowbase + wm * 64 + m * 16 + (l >> 4) * 4 + j;
                float s = 0.0f;
                #pragma unroll
                for (int n = 0; n < 4; n++) {
                    int gcol = colbase + wn * 64 + n * 16 + (l & 15);
                    float v = acc[m][n][j];
                    float e = exp2f(v * IT2);
                    s += (grow == gcol) ? 1.0f : e;
                }
                sums[m][j] += s;
            }
        }
    }

    /* reduce across the 16 lanes (l&15) holding different columns */
    #pragma unroll
    for (int m = 0; m < 4; m++)
        #pragma unroll
        for (int j = 0; j < 4; j++) {
            float v = sums[m][j];
            v += __shfl_xor(v, 1);
            v += __shfl_xor(v, 2);
            v += __shfl_xor(v, 4);
            v += __shfl_xor(v, 8);
            sums[m][j] = v;
        }

    if ((l & 15) == 0) {
        int part = split * 2 + wn;
        #pragma unroll
        for (int m = 0; m < 4; m++)
            #pragma unroll
            for (int j = 0; j < 4; j++) {
                int grow = rowbase + wm * 64 + m * 16 + (l >> 4) * 4 + j;
                parts[(size_t)part * N_ROWS + grow] = sums[m][j];
            }
    }
}

/* ---------------- kernel 4: den -> log(den), per-block partial sums ----- */
__global__ __launch_bounds__(256) void k_rowreduce(
        const float* __restrict__ parts, float* __restrict__ bsums) {
    int row = blockIdx.x * 256 + threadIdx.x;           /* grid 32 */
    float den = 0.0f;
    #pragma unroll 8
    for (int p = 0; p < NPARTS; p++) den += parts[(size_t)p * N_ROWS + row];
    float v = logf(den);
    #pragma unroll
    for (int m = 1; m < 64; m <<= 1) v += __shfl_xor(v, m);
    __shared__ float red[4];
    if ((threadIdx.x & 63) == 0) red[threadIdx.x >> 6] = v;
    __syncthreads();
    if (threadIdx.x == 0)
        bsums[blockIdx.x] = red[0] + red[1] + red[2] + red[3];
}

/* ---------------- kernel 5: final scalar ------------------------------- */
__global__ __launch_bounds__(256) void k_final(
        const float* __restrict__ bsums, const float* __restrict__ posv,
        float* __restrict__ out) {
    int t = threadIdx.x;
    float ps = 0.0f;
    for (int i = t; i < B_ROWS; i += 256) ps += posv[i];
    float lg = (t < 32) ? bsums[t] : 0.0f;
    /* total = sum(log den) - (1/T)*sum(pos) ; sum(pos) = 2*sum(posv), 1/T=2 */
    float comb = lg - 4.0f * ps;
    #pragma unroll
    for (int m = 1; m < 64; m <<= 1) comb += __shfl_xor(comb, m);
    __shared__ float red[4];
    if ((t & 63) == 0) red[t >> 6] = comb;
    __syncthreads();
    if (t == 0) out[0] = (red[0] + red[1] + red[2] + red[3]) / (float)N_ROWS;
}

extern "C" void kernel_launch(void* const* d_in, const int* in_sizes, int n_in,
                              void* d_out, int out_size, void* d_ws, size_t ws_size,
                              hipStream_t stream) {
    const float* feats  = (const float*)d_in[0];
    const float* tfeats = (const float*)d_in[1];
    float* out = (float*)d_out;
    char* ws = (char*)d_ws;

    ushort_t* Xb    = (ushort_t*)ws;                        /* 4 MB          */
    float*    norms = (float*)(ws + 4194304);               /* 32 KB         */
    float*    posv  = (float*)(ws + 4227072);               /* 16 KB         */
    float*    parts = (float*)(ws + 4243456);               /* 2 MB          */
    float*    bsums = (float*)(ws + 6340608);               /* 128 B         */

    k_normalize<<<N_ROWS / 4, 256, 0, stream>>>(feats, tfeats, Xb, norms);
    k_pos      <<<B_ROWS / 4, 256, 0, stream>>>(feats, tfeats, norms, posv);
    k_gemm     <<<64 * SPLITS, 256, 0, stream>>>(Xb, parts);
    k_rowreduce<<<N_ROWS / 256, 256, 0, stream>>>(parts, bsums);
    k_final    <<<1, 256, 0, stream>>>(bsums, posv, out);
}

// Round 2
// 115.871 us; speedup vs baseline: 1.0324x; 1.0324x over previous
//
#include <hip/hip_runtime.h>

#define B_ROWS 4096
#define N_ROWS 8192
#define DDIM   256
#define IT2    2.885390081777927f   /* 1/(T*ln2), T=0.5 */

#define BM 128
#define BK 64
#define NTILE 64                    /* N_ROWS / BM */
#define NBLK  2080                  /* NTILE*(NTILE+1)/2 upper-tri tiles */
#define NPARTS 128                  /* 2 slots per tile-index */

typedef unsigned short ushort_t;
typedef __bf16 bf16x8 __attribute__((ext_vector_type(8)));
typedef float  f32x4  __attribute__((ext_vector_type(4)));

__device__ __forceinline__ ushort_t f2bf(float x) {
    union { float f; unsigned u; } a; a.f = x;
    unsigned r = a.u + 0x7fffu + ((a.u >> 16) & 1u);   /* RNE */
    return (ushort_t)(r >> 16);
}

__device__ __forceinline__ void gload_lds16(const void* g, void* l) {
    __builtin_amdgcn_global_load_lds(
        (const __attribute__((address_space(1))) unsigned int*)g,
        (__attribute__((address_space(3))) unsigned int*)l,
        16, 0, 0);
}

/* ------- kernel 1: L2-normalize rows -> bf16 X, norms; fused pos ------- */
__global__ __launch_bounds__(256) void k_norm_pos(
        const float* __restrict__ feats, const float* __restrict__ tfeats,
        ushort_t* __restrict__ Xb, float* __restrict__ posv) {
    __shared__ float fbuf[2][DDIM];
    __shared__ float nsh[4];
    int w = threadIdx.x >> 6, l = threadIdx.x & 63;
    int i0 = blockIdx.x * 2;                         /* grid 2048 */
    int pair = (w < 2) ? w : (w - 2);
    int row  = (w < 2) ? (i0 + pair) : (i0 + pair + B_ROWS);
    const float* src = (w < 2) ? feats + (size_t)(i0 + pair) * DDIM
                               : tfeats + (size_t)(i0 + pair) * DDIM;
    float4 v = ((const float4*)src)[l];
    float ss = v.x*v.x + v.y*v.y + v.z*v.z + v.w*v.w;
    #pragma unroll
    for (int m = 1; m < 64; m <<= 1) ss += __shfl_xor(ss, m);
    float nrm = fmaxf(sqrtf(ss), 1e-12f);
    float inv = 1.0f / nrm;
    ushort4 o;
    o.x = f2bf(v.x * inv); o.y = f2bf(v.y * inv);
    o.z = f2bf(v.z * inv); o.w = f2bf(v.w * inv);
    ((ushort4*)(Xb + (size_t)row * DDIM))[l] = o;
    if (w < 2) ((float4*)fbuf[pair])[l] = v;
    if (l == 0) nsh[w] = nrm;
    __syncthreads();
    if (w >= 2) {
        float4 a = ((const float4*)fbuf[pair])[l];
        float d = a.x*v.x + a.y*v.y + a.z*v.z + a.w*v.w;
        #pragma unroll
        for (int m = 1; m < 64; m <<= 1) d += __shfl_xor(d, m);
        if (l == 0) posv[i0 + pair] = d / (nsh[pair] * nsh[w]);
    }
}

/* ------- kernel 2: triangular fused sim-GEMM + exp + row/col sums ------ */
__global__ __launch_bounds__(256) void k_gemm(
        const ushort_t* __restrict__ Xb, float* __restrict__ parts) {
    __shared__ ushort_t ldsA[BM * BK];   /* 16 KB, swizzled content */
    __shared__ ushort_t ldsB[BM * BK];

    /* blockIdx -> upper-triangle tile (rt, ct), rt <= ct */
    int idx = blockIdx.x;
    int rt = 0;
    while (idx >= (NTILE - rt)) { idx -= (NTILE - rt); rt++; }
    int ct = rt + idx;
    bool isdiag = (rt == ct);

    int rowbase = rt * BM;
    int colbase = ct * BM;
    int t = threadIdx.x;
    int l = t & 63;
    int w = t >> 6;
    int wm = w >> 1, wn = w & 1;

    f32x4 acc[4][4];
    #pragma unroll
    for (int m = 0; m < 4; m++)
        #pragma unroll
        for (int n = 0; n < 4; n++) acc[m][n] = (f32x4){0.f, 0.f, 0.f, 0.f};

    for (int kb = 0; kb < DDIM; kb += BK) {
        /* stage A[128][64] and B[128][64] bf16; pre-swizzled source so the
           linear global_load_lds dest matches the XOR-swizzled read */
        #pragma unroll
        for (int i = 0; i < 4; i++) {
            int o   = (i * 256 + t) * 16;          /* byte off in 16 KB  */
            int row = o >> 7;
            int cb  = o & 127;
            int scb = cb ^ ((row & 7) << 4);
            const char* ga = (const char*)Xb +
                ((size_t)(rowbase + row) * DDIM + kb) * 2 + scb;
            gload_lds16(ga, (char*)ldsA + o);
            const char* gb = (const char*)Xb +
                ((size_t)(colbase + row) * DDIM + kb) * 2 + scb;
            gload_lds16(gb, (char*)ldsB + o);
        }
        __syncthreads();

        #pragma unroll
        for (int ks = 0; ks < 2; ks++) {
            bf16x8 af[4], bfr[4];
            int cbw = ((l >> 4) * 16) + ks * 64;
            #pragma unroll
            for (int m = 0; m < 4; m++) {
                int row  = wm * 64 + m * 16 + (l & 15);
                int addr = row * 128 + (cbw ^ ((row & 7) << 4));
                af[m] = *(const bf16x8*)((const char*)ldsA + addr);
            }
            #pragma unroll
            for (int n = 0; n < 4; n++) {
                int row  = wn * 64 + n * 16 + (l & 15);
                int addr = row * 128 + (cbw ^ ((row & 7) << 4));
                bfr[n] = *(const bf16x8*)((const char*)ldsB + addr);
            }
            #pragma unroll
            for (int m = 0; m < 4; m++)
                #pragma unroll
                for (int n = 0; n < 4; n++)
                    acc[m][n] = __builtin_amdgcn_mfma_f32_16x16x32_bf16(
                        af[m], bfr[n], acc[m][n], 0, 0, 0);
        }
        __syncthreads();
    }

    /* epilogue: e = exp2(sim*IT2); diag tile -> 1.0 on the diagonal.
       Row sums feed rows of block rt; col sums feed rows of block ct. */
    float rs[4][4];
    float cs[4];
    #pragma unroll
    for (int m = 0; m < 4; m++)
        #pragma unroll
        for (int j = 0; j < 4; j++) rs[m][j] = 0.0f;
    #pragma unroll
    for (int n = 0; n < 4; n++) cs[n] = 0.0f;

    #pragma unroll
    for (int m = 0; m < 4; m++) {
        #pragma unroll
        for (int j = 0; j < 4; j++) {
            int grow = rowbase + wm * 64 + m * 16 + (l >> 4) * 4 + j;
            #pragma unroll
            for (int n = 0; n < 4; n++) {
                int gcol = colbase + wn * 64 + n * 16 + (l & 15);
                float e = exp2f(acc[m][n][j] * IT2);
                if (isdiag && grow == gcol) e = 1.0f;
                rs[m][j] += e;
                cs[n]    += e;
            }
        }
    }

    /* row sums: reduce across lanes 0-15 (columns), write slot ct*2+wn */
    #pragma unroll
    for (int m = 0; m < 4; m++)
        #pragma unroll
        for (int j = 0; j < 4; j++) {
            float v = rs[m][j];
            v += __shfl_xor(v, 1);
            v += __shfl_xor(v, 2);
            v += __shfl_xor(v, 4);
            v += __shfl_xor(v, 8);
            if ((l & 15) == 0) {
                int grow = rowbase + wm * 64 + m * 16 + (l >> 4) * 4 + j;
                parts[(size_t)(ct * 2 + wn) * N_ROWS + grow] = v;
            }
        }

    /* col sums: reduce across lane groups (rows), write slot rt*2+wm */
    if (!isdiag) {
        #pragma unroll
        for (int n = 0; n < 4; n++) {
            float v = cs[n];
            v += __shfl_xor(v, 16);
            v += __shfl_xor(v, 32);
            if (l < 16) {
                int gcol = colbase + wn * 64 + n * 16 + l;
                parts[(size_t)(rt * 2 + wm) * N_ROWS + gcol] = v;
            }
        }
    }
}

/* ------- kernel 3: den -> log(den), per-block partial sums ------------- */
__global__ __launch_bounds__(256) void k_rowreduce(
        const float* __restrict__ parts, float* __restrict__ bsums) {
    int row = blockIdx.x * 256 + threadIdx.x;           /* grid 32 */
    float den = 0.0f;
    #pragma unroll 8
    for (int p = 0; p < NPARTS; p++) den += parts[(size_t)p * N_ROWS + row];
    float v = logf(den);
    #pragma unroll
    for (int m = 1; m < 64; m <<= 1) v += __shfl_xor(v, m);
    __shared__ float red[4];
    if ((threadIdx.x & 63) == 0) red[threadIdx.x >> 6] = v;
    __syncthreads();
    if (threadIdx.x == 0)
        bsums[blockIdx.x] = red[0] + red[1] + red[2] + red[3];
}

/* ------- kernel 4: final scalar ---------------------------------------- */
__global__ __launch_bounds__(256) void k_final(
        const float* __restrict__ bsums, const float* __restrict__ posv,
        float* __restrict__ out) {
    int t = threadIdx.x;
    float ps = 0.0f;
    for (int i = t; i < B_ROWS; i += 256) ps += posv[i];
    float lg = (t < 32) ? bsums[t] : 0.0f;
    /* total = sum(log den) - (1/T)*sum(pos); sum(pos)=2*sum(posv), 1/T=2 */
    float comb = lg - 4.0f * ps;
    #pragma unroll
    for (int m = 1; m < 64; m <<= 1) comb += __shfl_xor(comb, m);
    __shared__ float red[4];
    if ((t & 63) == 0) red[t >> 6] = comb;
    __syncthreads();
    if (t == 0) out[0] = (red[0] + red[1] + red[2] + red[3]) / (float)N_ROWS;
}

extern "C" void kernel_launch(void* const* d_in, const int* in_sizes, int n_in,
                              void* d_out, int out_size, void* d_ws, size_t ws_size,
                              hipStream_t stream) {
    const float* feats  = (const float*)d_in[0];
    const float* tfeats = (const float*)d_in[1];
    float* out = (float*)d_out;
    char* ws = (char*)d_ws;

    ushort_t* Xb    = (ushort_t*)ws;                        /* 4 MB          */
    float*    posv  = (float*)(ws + 4194304);               /* 16 KB         */
    float*    parts = (float*)(ws + 4210688);               /* 4 MB          */
    float*    bsums = (float*)(ws + 8404992);               /* 128 B         */

    k_norm_pos <<<B_ROWS / 2, 256, 0, stream>>>(feats, tfeats, Xb, posv);
    k_gemm     <<<NBLK, 256, 0, stream>>>(Xb, parts);
    k_rowreduce<<<N_ROWS / 256, 256, 0, stream>>>(parts, bsums);
    k_final    <<<1, 256, 0, stream>>>(bsums, posv, out);
}